// Round 2
// baseline (83.878 us; speedup 1.0000x reference)
//
#include <hip/hip_runtime.h>

// YOLO v1 loss on MI355X — direct-load version, no LDS staging.
// bounding_boxes (8192,7,7,30) f32, ground_truth (8192,7,7,30) f32.
// Output: 6 float32 scalars.
//
// Each thread owns a PAIR of adjacent cells: 2*30 floats = 240 B = 15 float4,
// perfectly 16-B aligned. Loaded as two overlapping 8-float4 windows
// (cell0 = window@f4[0..7] offset 0; cell1 = window@f4[7..14] offset 2 floats)
// so all register-array indices are compile-time constants.

#define CH 30
#define NCELLS (8192 * 49)      // 401408
#define NPAIRS (NCELLS / 2)     // 200704
#define BLK 256
#define NBLOCKS (NPAIRS / BLK)  // 784 exactly

__device__ __forceinline__ float iou_one(const float* __restrict__ B,
                                         const float* __restrict__ G,
                                         float fx, float fy) {
    float px = truncf((B[0] + fx) * 64.0f);
    float py = truncf((B[1] + fy) * 64.0f);
    float pw = truncf(B[2] * 448.0f);
    float ph = truncf(B[3] * 448.0f);
    float x1 = fmaxf(0.0f, px - pw * 0.5f);
    float y1 = fmaxf(0.0f, py - ph * 0.5f);
    float x2 = fminf(447.0f, px + pw * 0.5f);
    float y2 = fminf(447.0f, py + ph * 0.5f);
    float parea = (x2 - x1) * (y2 - y1);
    float lx = fmaxf(x1, G[5]);
    float rx = fminf(x2, G[7]);
    float uy = fmaxf(y1, G[6]);
    float dy = fminf(y2, G[8]);
    float inter = (rx - lx) * (dy - uy);
    bool valid = (rx >= lx) && (dy >= uy);
    return valid ? inter / (parea + G[9] - inter) : 0.0f;
}

__global__ __launch_bounds__(256) void yolo_v1_loss_kernel(
    const float* __restrict__ bb, const float* __restrict__ gt,
    float* __restrict__ out) {
    __shared__ float sRed[4][6];

    const int tid = threadIdx.x;
    const int pair = blockIdx.x * BLK + tid;  // 0 .. NPAIRS-1
    const int cell0 = pair * 2;

    const float4* pb = (const float4*)bb + (size_t)pair * 15;
    const float4* pg = (const float4*)gt + (size_t)pair * 15;

    float a_loss = 0.f, a_coord = 0.f, a_conf = 0.f, a_cls = 0.f,
          a_iou = 0.f, a_obj = 0.f;

#pragma unroll
    for (int c = 0; c < 2; ++c) {
        // window: cell0 -> f4[0..7] (cell floats at idx 0..29)
        //         cell1 -> f4[7..14] (cell floats at idx 2..31)
        float vb[32], vg[32];
#pragma unroll
        for (int i = 0; i < 8; ++i) {
            *(float4*)(vb + 4 * i) = pb[7 * c + i];
            *(float4*)(vg + 4 * i) = pg[7 * c + i];
        }
        const float* B = vb + (c ? 2 : 0);
        const float* G = vg + (c ? 2 : 0);

        int cell = cell0 + c;
        int b = cell / 49;
        int rem = cell - b * 49;
        int gy = rem / 7;
        int gx = rem - gy * 7;
        float fx = (float)gx, fy = (float)gy;

        float iou1 = iou_one(B, G, fx, fy);
        float iou2 = iou_one(B + 5, G, fx, fy);
        bool r1 = iou1 > iou2;
        const float* P = r1 ? B : (B + 5);   // responsible box
        const float* Nb = r1 ? (B + 5) : B;  // the other box
        float iou = r1 ? iou1 : iou2;

        float fm = (rintf(G[4]) != 0.0f) ? 1.0f : 0.0f;

        float noobj = 0.5f * (B[4] * B[4] + B[9] * B[9]);

        float dx = P[0] - G[0];
        float dyv = P[1] - G[1];
        float dw = sqrtf(P[2]) - sqrtf(G[2]);
        float dh = sqrtf(P[3]) - sqrtf(G[3]);
        float coord = 5.0f * (dx * dx + dyv * dyv + dw * dw + dh * dh);

        float dc = P[4] - iou;
        float conf = dc * dc + 0.5f * Nb[4] * Nb[4];

        float cls = 0.f;
#pragma unroll
        for (int k = 0; k < 20; ++k) {
            float d = G[10 + k] - B[10 + k];
            cls += d * d;
        }

        float ifm = 1.0f - fm;
        a_loss += fm * (coord + conf + cls) + ifm * noobj;
        a_coord += fm * coord;
        a_conf += fm * conf + ifm * noobj;
        a_cls += fm * cls;
        a_iou += fm * iou;
        a_obj += fm;
    }

    // ---- wave reduce (64-wide) ----
#pragma unroll
    for (int off = 32; off > 0; off >>= 1) {
        a_loss += __shfl_down(a_loss, off);
        a_coord += __shfl_down(a_coord, off);
        a_conf += __shfl_down(a_conf, off);
        a_cls += __shfl_down(a_cls, off);
        a_iou += __shfl_down(a_iou, off);
        a_obj += __shfl_down(a_obj, off);
    }
    int wave = tid >> 6;
    int lane = tid & 63;
    if (lane == 0) {
        sRed[wave][0] = a_loss;
        sRed[wave][1] = a_coord;
        sRed[wave][2] = a_conf;
        sRed[wave][3] = a_cls;
        sRed[wave][4] = a_iou;
        sRed[wave][5] = a_obj;
    }
    __syncthreads();
    if (tid == 0) {
#pragma unroll
        for (int j = 0; j < 6; ++j) {
            float v = sRed[0][j] + sRed[1][j] + sRed[2][j] + sRed[3][j];
            atomicAdd(&out[j], v);
        }
    }
}

extern "C" void kernel_launch(void* const* d_in, const int* in_sizes, int n_in,
                              void* d_out, int out_size, void* d_ws,
                              size_t ws_size, hipStream_t stream) {
    const float* bb = (const float*)d_in[0];
    const float* gt = (const float*)d_in[1];
    float* out = (float*)d_out;
    hipMemsetAsync(out, 0, out_size * sizeof(float), stream);
    yolo_v1_loss_kernel<<<NBLOCKS, BLK, 0, stream>>>(bb, gt, out);
}

// Round 3
// 27.598 us; speedup vs baseline: 3.0393x; 3.0393x over previous
//
#include <hip/hip_runtime.h>

// YOLO v1 loss on MI355X — round 3.
// Direct float4 loads (all hoisted, one vmcnt wait), block partials to
// workspace, separate 6-wave reduction kernel (no contended atomics).
// bounding_boxes (8192,7,7,30) f32, ground_truth (8192,7,7,30) f32.
// Output: 6 float32 scalars.

#define CH 30
#define NCELLS (8192 * 49)      // 401408
#define NPAIRS (NCELLS / 2)     // 200704
#define BLK 256
#define NBLOCKS (NPAIRS / BLK)  // 784 exactly

__device__ __forceinline__ float iou_one(const float* __restrict__ B,
                                         const float* __restrict__ G,
                                         float fx, float fy) {
    float px = truncf((B[0] + fx) * 64.0f);
    float py = truncf((B[1] + fy) * 64.0f);
    float pw = truncf(B[2] * 448.0f);
    float ph = truncf(B[3] * 448.0f);
    float x1 = fmaxf(0.0f, px - pw * 0.5f);
    float y1 = fmaxf(0.0f, py - ph * 0.5f);
    float x2 = fminf(447.0f, px + pw * 0.5f);
    float y2 = fminf(447.0f, py + ph * 0.5f);
    float parea = (x2 - x1) * (y2 - y1);
    float lx = fmaxf(x1, G[5]);
    float rx = fminf(x2, G[7]);
    float uy = fmaxf(y1, G[6]);
    float dy = fminf(y2, G[8]);
    float inter = (rx - lx) * (dy - uy);
    bool valid = (rx >= lx) && (dy >= uy);
    return valid ? inter / (parea + G[9] - inter) : 0.0f;
}

__global__ __launch_bounds__(256) void yolo_v1_loss_main(
    const float* __restrict__ bb, const float* __restrict__ gt,
    float* __restrict__ ws) {
    __shared__ float sRed[4][6];

    const int tid = threadIdx.x;
    const int pair = blockIdx.x * BLK + tid;  // 0 .. NPAIRS-1

    const float4* pb = (const float4*)bb + (size_t)pair * 15;
    const float4* pg = (const float4*)gt + (size_t)pair * 15;

    // ---- hoist ALL loads: 30 independent float4, one wait ----
    float vb[60], vg[60];
#pragma unroll
    for (int i = 0; i < 15; ++i) {
        *(float4*)(vb + 4 * i) = pb[i];
        *(float4*)(vg + 4 * i) = pg[i];
    }

    float a_loss = 0.f, a_coord = 0.f, a_conf = 0.f, a_cls = 0.f,
          a_iou = 0.f, a_obj = 0.f;

#pragma unroll
    for (int c = 0; c < 2; ++c) {
        const float* B = vb + 30 * c;
        const float* G = vg + 30 * c;

        int cell = pair * 2 + c;
        int b = cell / 49;
        int rem = cell - b * 49;
        int gy = rem / 7;
        int gx = rem - gy * 7;
        float fx = (float)gx, fy = (float)gy;

        float iou1 = iou_one(B, G, fx, fy);
        float iou2 = iou_one(B + 5, G, fx, fy);
        bool r1 = iou1 > iou2;
        const float* P = r1 ? B : (B + 5);   // responsible box
        const float* Nb = r1 ? (B + 5) : B;  // the other box
        float iou = r1 ? iou1 : iou2;

        float fm = (rintf(G[4]) != 0.0f) ? 1.0f : 0.0f;

        float noobj = 0.5f * (B[4] * B[4] + B[9] * B[9]);

        float dx = P[0] - G[0];
        float dyv = P[1] - G[1];
        float dw = sqrtf(P[2]) - sqrtf(G[2]);
        float dh = sqrtf(P[3]) - sqrtf(G[3]);
        float coord = 5.0f * (dx * dx + dyv * dyv + dw * dw + dh * dh);

        float dc = P[4] - iou;
        float conf = dc * dc + 0.5f * Nb[4] * Nb[4];

        float cls = 0.f;
#pragma unroll
        for (int k = 0; k < 20; ++k) {
            float d = G[10 + k] - B[10 + k];
            cls += d * d;
        }

        float ifm = 1.0f - fm;
        a_loss += fm * (coord + conf + cls) + ifm * noobj;
        a_coord += fm * coord;
        a_conf += fm * conf + ifm * noobj;
        a_cls += fm * cls;
        a_iou += fm * iou;
        a_obj += fm;
    }

    // ---- wave reduce (64-wide) ----
#pragma unroll
    for (int off = 32; off > 0; off >>= 1) {
        a_loss += __shfl_down(a_loss, off);
        a_coord += __shfl_down(a_coord, off);
        a_conf += __shfl_down(a_conf, off);
        a_cls += __shfl_down(a_cls, off);
        a_iou += __shfl_down(a_iou, off);
        a_obj += __shfl_down(a_obj, off);
    }
    int wave = tid >> 6;
    int lane = tid & 63;
    if (lane == 0) {
        sRed[wave][0] = a_loss;
        sRed[wave][1] = a_coord;
        sRed[wave][2] = a_conf;
        sRed[wave][3] = a_cls;
        sRed[wave][4] = a_iou;
        sRed[wave][5] = a_obj;
    }
    __syncthreads();
    if (tid == 0) {
#pragma unroll
        for (int j = 0; j < 6; ++j) {
            float v = sRed[0][j] + sRed[1][j] + sRed[2][j] + sRed[3][j];
            ws[j * NBLOCKS + blockIdx.x] = v;  // transposed: coalesced in k2
        }
    }
}

// 6 waves, wave j reduces the 784 partials of output j.
__global__ __launch_bounds__(384) void yolo_v1_loss_reduce(
    const float* __restrict__ ws, float* __restrict__ out) {
    const int tid = threadIdx.x;
    const int j = tid >> 6;    // 0..5
    const int lane = tid & 63;
    float s = 0.f;
    for (int i = lane; i < NBLOCKS; i += 64) s += ws[j * NBLOCKS + i];
#pragma unroll
    for (int off = 32; off > 0; off >>= 1) s += __shfl_down(s, off);
    if (lane == 0) out[j] = s;
}

extern "C" void kernel_launch(void* const* d_in, const int* in_sizes, int n_in,
                              void* d_out, int out_size, void* d_ws,
                              size_t ws_size, hipStream_t stream) {
    const float* bb = (const float*)d_in[0];
    const float* gt = (const float*)d_in[1];
    float* out = (float*)d_out;
    float* ws = (float*)d_ws;
    yolo_v1_loss_main<<<NBLOCKS, BLK, 0, stream>>>(bb, gt, ws);
    yolo_v1_loss_reduce<<<1, 384, 0, stream>>>(ws, out);
}